// Round 12
// baseline (274.534 us; speedup 1.0000x reference)
//
#include <hip/hip_runtime.h>
#include <cstdint>
#include <cstddef>

#define H_IN   1024
#define H_OUTD 1024
#define PDIM   512
#define BSZ    16
#define LSEQ   1024
#define BLM    (BSZ * LSEQ)   // 16384 rows
#define CCH    32             // chunks along L
#define CLEN   32             // steps per chunk (CCH*CLEN == LSEQ)
#define SCAN_MAGIC 0x53355AA1u

typedef __bf16 bf16_t;
typedef __bf16 bf16x8 __attribute__((ext_vector_type(8)));
typedef float  floatx4 __attribute__((ext_vector_type(4)));

// exact RNE fp32 -> bf16 bit conversion
__device__ __forceinline__ unsigned short f2bf(float f) {
    unsigned u = __float_as_uint(f);
    u = u + 0x7fffu + ((u >> 16) & 1u);
    return (unsigned short)(u >> 16);
}
__device__ __forceinline__ float bf2f(unsigned short s) {
    return __uint_as_float((unsigned)s << 16);
}

__device__ __forceinline__ void gl_lds16(const void* g, void* l) {
    __builtin_amdgcn_global_load_lds(
        (const __attribute__((address_space(1))) void*)g,
        (__attribute__((address_space(3))) void*)l, 16, 0, 0);
}

// ---------------- fused setup: per-p constants + u/B/C fp32->bf16 casts
#define NU4 (BLM * H_IN / 4)
#define NB4 (PDIM * H_IN / 4)
#define NC4 (H_OUTD * PDIM / 4)
__global__ void setup_kernel(const float* __restrict__ Lraw,
                             const float* __restrict__ lstep,
                             float* __restrict__ stepv,
                             float* __restrict__ lamv,
                             const float4* __restrict__ Usrc,
                             ushort4* __restrict__ Udst,
                             const float4* __restrict__ Bsrc,
                             ushort4* __restrict__ Bdst,
                             const float4* __restrict__ Csrc,
                             ushort4* __restrict__ Cdst) {
    const int gid = blockIdx.x * 256 + threadIdx.x;
    if (gid < PDIM) {
        stepv[gid] = expf(lstep[gid]);  // STEP_RESCALE = 1.0
        float x = Lraw[gid];
        // jax.nn.softplus(x) = max(x,0) + log1p(exp(-|x|))
        float sp = fmaxf(x, 0.0f) + log1pf(expf(-fabsf(x)));
        lamv[gid] = -(sp + 1e-3f);
    }
    if (gid < NU4) {
        float4 v = Usrc[gid];
        ushort4 o;
        o.x = f2bf(v.x); o.y = f2bf(v.y); o.z = f2bf(v.z); o.w = f2bf(v.w);
        Udst[gid] = o;
    } else {
        const int g2 = gid - NU4;
        if (g2 < NB4) {
            float4 v = Bsrc[g2];
            ushort4 o;
            o.x = f2bf(v.x); o.y = f2bf(v.y); o.z = f2bf(v.z); o.w = f2bf(v.w);
            Bdst[g2] = o;
        } else if (g2 < NB4 + NC4) {
            const int g3 = g2 - NB4;
            float4 v = Csrc[g3];
            ushort4 o;
            o.x = f2bf(v.x); o.y = f2bf(v.y); o.z = f2bf(v.z); o.w = f2bf(v.w);
            Cdst[g3] = o;
        }
    }
}

// ---------------- NT bf16 MFMA GEMM: out[m,n] = sum_k A[m,k]*Bm[n,k]
// EPI==1: += Dv[n]*U32[m,n], with the U load exec-masked out when Dv[n]==0
// (true for this problem -> saves the 32 MB U fetch, correct for any D).
// OUTBF==1: store bf16 to Cb, else fp32 to Cf.
// 128x128 tile, BK=32, 256 threads (4 waves, each 64x64), 16x16x32 MFMA.
// Single-barrier double-buffer schedule + conflict-free LDS swizzle
// g(row)=(row+(row>>2))&3 (measured win, r7: 192.8 -> 189.2).
// 1D grid, XCD-aware swizzle (GXL = log2 of n-blocks).
template<int EPI, int OUTBF, int GXL>
__global__ __launch_bounds__(256, 4)
void gemm_nt(const bf16_t* __restrict__ A, const bf16_t* __restrict__ Bm,
             float* __restrict__ Cf, unsigned short* __restrict__ Cb,
             int M, int N, int K,
             const float* __restrict__ Dv, const float* __restrict__ U32) {
    __shared__ bf16_t As[2 * 4096];
    __shared__ bf16_t Bs[2 * 4096];

    const int i     = blockIdx.x;
    const int n_blk = (i >> 3) & ((1 << GXL) - 1);
    const int m_blk = ((i >> (3 + GXL)) << 3) | (i & 7);
    const int m0    = m_blk << 7;
    const int n0    = n_blk << 7;

    const int tid  = threadIdx.x;
    const int lane = tid & 63;
    const int w    = tid >> 6;
    const int wm   = (w & 1) << 6;
    const int wn   = (w >> 1) << 6;
    const int r16  = lane & 15;
    const int q    = lane >> 4;
    // conflict-free fragment slot: slot = q ^ g(r16), g(r)=(r+(r>>2))&3
    const int fsw  = ((q ^ ((r16 + (r16 >> 2)) & 3)) << 3);

    // staging: each wave covers 32 rows of each tile via two 16-row chunks;
    // lane l -> row srow = l>>2, k-seg = (l&3) ^ g(srow)
    const int srow = lane >> 2;              // 0..15 within chunk
    const int seg  = (lane & 3) ^ ((srow + (srow >> 2)) & 3);
    const int c0   = w * 32;
    const int c1   = c0 + 16;

    const bf16_t* gA0 = A  + (size_t)(m0 + c0 + srow) * K + seg * 8;
    const bf16_t* gA1 = A  + (size_t)(m0 + c1 + srow) * K + seg * 8;
    const bf16_t* gB0 = Bm + (size_t)(n0 + c0 + srow) * K + seg * 8;
    const bf16_t* gB1 = Bm + (size_t)(n0 + c1 + srow) * K + seg * 8;
    bf16_t* lA0 = &As[c0 * 32];              // buffer-0 destinations
    bf16_t* lA1 = &As[c1 * 32];
    bf16_t* lB0 = &Bs[c0 * 32];
    bf16_t* lB1 = &Bs[c1 * 32];

    floatx4 acc[4][4] = {};

    // prologue: stage K-tile 0 into buffer 0
    gl_lds16(gA0, lA0);
    gl_lds16(gA1, lA1);
    gl_lds16(gB0, lB0);
    gl_lds16(gB1, lB1);
    __syncthreads();   // drains vmcnt(0): tile 0 resident

    int cur = 0;
    for (int k0 = 0; k0 < K; k0 += 32) {
        const int nxt = cur ^ 1;
        // issue next K-tile stage FIRST (in flight during ds_read+MFMA below)
        if (k0 + 32 < K) {
            gl_lds16(gA0 + k0 + 32, lA0 + nxt * 4096);
            gl_lds16(gA1 + k0 + 32, lA1 + nxt * 4096);
            gl_lds16(gB0 + k0 + 32, lB0 + nxt * 4096);
            gl_lds16(gB1 + k0 + 32, lB1 + nxt * 4096);
        }

        const bf16_t* rA = As + cur * 4096;
        const bf16_t* rB = Bs + cur * 4096;
        bf16x8 af[4], bfr[4];
#pragma unroll
        for (int ii = 0; ii < 4; ++ii) {
            af[ii]  = *(const bf16x8*)&rA[(wm + ii * 16 + r16) * 32 + fsw];
            bfr[ii] = *(const bf16x8*)&rB[(wn + ii * 16 + r16) * 32 + fsw];
        }
#pragma unroll
        for (int mi = 0; mi < 4; ++mi)
#pragma unroll
            for (int ni = 0; ni < 4; ++ni)
                acc[mi][ni] = __builtin_amdgcn_mfma_f32_16x16x32_bf16(
                    af[mi], bfr[ni], acc[mi][ni], 0, 0, 0);

        // single barrier per K-step: (a) drains the prefetch (vmcnt(0)) AFTER
        // it overlapped with compute; (b) all waves done reading cur before
        // the next iteration overwrites it.
        __syncthreads();
        cur = nxt;
    }

    // epilogue: C/D layout row = q*4 + e, col = r16 (verified)
    float dn[4];
    if (EPI == 1) {
#pragma unroll
        for (int ni = 0; ni < 4; ++ni) dn[ni] = Dv[n0 + wn + ni * 16 + r16];
    }
#pragma unroll
    for (int mi = 0; mi < 4; ++mi) {
#pragma unroll
        for (int e = 0; e < 4; ++e) {
            const int m = m0 + wm + mi * 16 + q * 4 + e;
#pragma unroll
            for (int ni = 0; ni < 4; ++ni) {
                const int n = n0 + wn + ni * 16 + r16;
                const size_t idx = (size_t)m * N + n;
                float v = acc[mi][ni][e];
                if (EPI == 1) {
                    if (dn[ni] != 0.0f) v += dn[ni] * U32[idx];
                }
                if (OUTBF == 1) Cb[idx] = f2bf(v);
                else            Cf[idx] = v;
            }
        }
    }
}

// ---------------- single-pass chunked scan (decoupled aggregates).
// Recurrence: x_l = abar_l * x_{l-1} + gamma_l * bu_l  (== reference form).
// One kernel replaces scan_part1 + scan_part23:
//   phase 1: block (c,b) computes chunk aggregate (P,S), publishes it
//            (stores + __threadfence release + agent-scope MAGIC flag);
//   wait:    threads 0..c-1 poll predecessor flags in parallel;
//   phase 2: compose entering state (4-wide associative tree, agent-scope
//            relaxed atomic loads -> immune to per-XCD L2 staleness),
//            replay chunk from L2-hot Bu, emit bf16 X.
// Deadlock-free WITHOUT dispatch-order assumptions: 512 blocks x 512 thr at
// __launch_bounds__(512,4) (VGPR<=128, LDS 0) = 2 blocks/CU -> all 512
// co-resident. Flags live in workspace: harness re-poisons ws every
// iteration, so flags auto-reset between replays (poison != MAGIC).
__global__ __launch_bounds__(512, 4)
void scan_fused(const unsigned short* __restrict__ Bu, const float* __restrict__ ts,
                const float* __restrict__ stepv, const float* __restrict__ lamv,
                float* __restrict__ Pagg, float* __restrict__ Sagg,
                unsigned int* __restrict__ flags,
                unsigned short* __restrict__ Xbf) {
    const int bid = blockIdx.x;
    const int c = bid & (CCH - 1);
    const int b = bid >> 5;
    const int p = threadIdx.x;

    const float lam  = lamv[p];
    const float stp  = stepv[p];
    const float rlam = 1.0f / lam;
    const bool  lam_big = fabsf(lam) > 1e-6f;

    const unsigned short* bu = Bu + ((size_t)b * LSEQ + c * CLEN) * PDIM + p;
    const float* tb = ts + b * LSEQ + c * CLEN;

    // ---- phase 1: chunk-local aggregate
    float P = 1.0f, S = 0.0f;
#pragma unroll 8
    for (int i = 0; i < CLEN; ++i) {
        float t     = tb[i];
        float delta = fmaxf(stp * t, 0.0f);
        float e     = fminf(lam * delta, 20.0f);
        float abar  = __expf(e);
        float gamma = lam_big ? (abar - 1.0f) * rlam : delta;
        S = fmaf(abar, S, gamma * bf2f(bu[(size_t)i * PDIM]));
        P *= abar;
    }
    const size_t o = ((size_t)b * CCH + c) * PDIM + p;
    Pagg[o] = P;
    Sagg[o] = S;
    __threadfence();                 // release: data visible device-wide
    __syncthreads();                 // all 512 threads' stores fenced
    if (p == 0)
        __hip_atomic_store(&flags[b * CCH + c], SCAN_MAGIC,
                           __ATOMIC_RELEASE, __HIP_MEMORY_SCOPE_AGENT);

    // ---- wait: parallel poll of the c predecessor flags
    if (p < c) {
        while (__hip_atomic_load(&flags[b * CCH + p],
                                 __ATOMIC_ACQUIRE, __HIP_MEMORY_SCOPE_AGENT)
               != SCAN_MAGIC) {}
    }
    __syncthreads();

    // ---- phase 2: entering state via associative composition
    //   (P0,S0) then (P1,S1) == (P0*P1, P1*S0 + S1)
    // agent-scope relaxed loads read from the device coherence point.
    float* Pb = Pagg + (size_t)b * CCH * PDIM + p;
    float* Sb = Sagg + (size_t)b * CCH * PDIM + p;
    float x = 0.0f;
    int cc = 0;
    for (; cc + 4 <= c; cc += 4) {
        float p0 = __hip_atomic_load(Pb + (size_t)(cc + 0) * PDIM, __ATOMIC_RELAXED, __HIP_MEMORY_SCOPE_AGENT);
        float s0 = __hip_atomic_load(Sb + (size_t)(cc + 0) * PDIM, __ATOMIC_RELAXED, __HIP_MEMORY_SCOPE_AGENT);
        float p1 = __hip_atomic_load(Pb + (size_t)(cc + 1) * PDIM, __ATOMIC_RELAXED, __HIP_MEMORY_SCOPE_AGENT);
        float s1 = __hip_atomic_load(Sb + (size_t)(cc + 1) * PDIM, __ATOMIC_RELAXED, __HIP_MEMORY_SCOPE_AGENT);
        float p2 = __hip_atomic_load(Pb + (size_t)(cc + 2) * PDIM, __ATOMIC_RELAXED, __HIP_MEMORY_SCOPE_AGENT);
        float s2 = __hip_atomic_load(Sb + (size_t)(cc + 2) * PDIM, __ATOMIC_RELAXED, __HIP_MEMORY_SCOPE_AGENT);
        float p3 = __hip_atomic_load(Pb + (size_t)(cc + 3) * PDIM, __ATOMIC_RELAXED, __HIP_MEMORY_SCOPE_AGENT);
        float s3 = __hip_atomic_load(Sb + (size_t)(cc + 3) * PDIM, __ATOMIC_RELAXED, __HIP_MEMORY_SCOPE_AGENT);
        float p01 = p0 * p1, s01 = fmaf(s0, p1, s1);
        float p23 = p2 * p3, s23 = fmaf(s2, p3, s3);
        float pq  = p01 * p23, sq = fmaf(s01, p23, s23);
        x = fmaf(pq, x, sq);
    }
    for (; cc < c; ++cc) {
        float pc = __hip_atomic_load(Pb + (size_t)cc * PDIM, __ATOMIC_RELAXED, __HIP_MEMORY_SCOPE_AGENT);
        float sc = __hip_atomic_load(Sb + (size_t)cc * PDIM, __ATOMIC_RELAXED, __HIP_MEMORY_SCOPE_AGENT);
        x = fmaf(pc, x, sc);
    }

    // ---- replay chunk (Bu/ts are L2-hot from phase 1), emit bf16
    unsigned short* xo = Xbf + ((size_t)b * LSEQ + c * CLEN) * PDIM + p;
#pragma unroll 8
    for (int i = 0; i < CLEN; ++i) {
        float t     = tb[i];
        float delta = fmaxf(stp * t, 0.0f);
        float e     = fminf(lam * delta, 20.0f);
        float abar  = __expf(e);
        float gamma = lam_big ? (abar - 1.0f) * rlam : delta;
        x = fmaf(abar, x, gamma * bf2f(bu[(size_t)i * PDIM]));
        xo[(size_t)i * PDIM] = f2bf(x);
    }
}

extern "C" void kernel_launch(void* const* d_in, const int* in_sizes, int n_in,
                              void* d_out, int out_size, void* d_ws, size_t ws_size,
                              hipStream_t stream) {
    (void)in_sizes; (void)n_in; (void)out_size; (void)ws_size;
    const float* u  = (const float*)d_in[0];
    const float* ts = (const float*)d_in[1];
    const float* Lr = (const float*)d_in[2];
    const float* ls = (const float*)d_in[3];
    const float* Bm = (const float*)d_in[4];
    const float* Cm = (const float*)d_in[5];
    const float* Dv = (const float*)d_in[6];
    float* out = (float*)d_out;

    char* ws = (char*)d_ws;
    bf16_t*         u_bf = (bf16_t*)(ws);                          // 32 MB
    bf16_t*         B_bf = (bf16_t*)(ws + (32u << 20));            // 1 MB
    bf16_t*         C_bf = (bf16_t*)(ws + (33u << 20));            // 1 MB
    unsigned short* Bu   = (unsigned short*)(ws + (34u << 20));    // 16 MB (bf16)
    unsigned short* X_bf = (unsigned short*)(ws + (50u << 20));    // 16 MB
    float*          Pagg = (float*)(ws + (66u << 20));             // 1 MB
    float*          Sagg = (float*)(ws + (67u << 20));             // 1 MB
    unsigned int*   flags= (unsigned int*)(ws + (68u << 20));      // 2 KB
    float*          stepv= (float*)(ws + (69u << 20));
    float*          lamv = stepv + PDIM;

    // consts + u/B/C casts fused
    setup_kernel<<<(NU4 + NB4 + NC4) / 256, 256, 0, stream>>>(
        Lr, ls, stepv, lamv,
        (const float4*)u,  (ushort4*)u_bf,
        (const float4*)Bm, (ushort4*)B_bf,
        (const float4*)Cm, (ushort4*)C_bf);

    // GEMM1: Bu[16384,512](bf16) = u_bf[16384,1024] . B_bf[512,1024]^T   (GXL=2: 4 n-blocks)
    gemm_nt<0, 1, 2><<<512, 256, 0, stream>>>(
        u_bf, B_bf, nullptr, Bu, BLM, PDIM, H_IN, nullptr, nullptr);

    // single-pass chunked scan -> X (bf16); 512 blocks all co-resident
    scan_fused<<<CCH * BSZ, 512, 0, stream>>>(Bu, ts, stepv, lamv,
                                              Pagg, Sagg, flags, X_bf);

    // GEMM2: out[16384,1024](fp32) = X_bf[16384,512] . C_bf[1024,512]^T + D*u  (GXL=3)
    gemm_nt<1, 0, 3><<<1024, 256, 0, stream>>>(
        (const bf16_t*)X_bf, C_bf, out, nullptr, BLM, H_OUTD, PDIM, Dv, u);
}

// Round 13
// 186.146 us; speedup vs baseline: 1.4748x; 1.4748x over previous
//
#include <hip/hip_runtime.h>
#include <cstdint>
#include <cstddef>

#define H_IN   1024
#define H_OUTD 1024
#define PDIM   512
#define BSZ    16
#define LSEQ   1024
#define BLM    (BSZ * LSEQ)   // 16384 rows
#define CCH    32             // chunks along L
#define CLEN   32             // steps per chunk (CCH*CLEN == LSEQ)

typedef __bf16 bf16_t;
typedef __bf16 bf16x8 __attribute__((ext_vector_type(8)));
typedef float  floatx4 __attribute__((ext_vector_type(4)));

// exact RNE fp32 -> bf16 bit conversion
__device__ __forceinline__ unsigned short f2bf(float f) {
    unsigned u = __float_as_uint(f);
    u = u + 0x7fffu + ((u >> 16) & 1u);
    return (unsigned short)(u >> 16);
}
__device__ __forceinline__ float bf2f(unsigned short s) {
    return __uint_as_float((unsigned)s << 16);
}

__device__ __forceinline__ void gl_lds16(const void* g, void* l) {
    __builtin_amdgcn_global_load_lds(
        (const __attribute__((address_space(1))) void*)g,
        (__attribute__((address_space(3))) void*)l, 16, 0, 0);
}

// ---------------- fused setup: per-p constants + u/B/C fp32->bf16 casts
#define NU4 (BLM * H_IN / 4)
#define NB4 (PDIM * H_IN / 4)
#define NC4 (H_OUTD * PDIM / 4)
__global__ void setup_kernel(const float* __restrict__ Lraw,
                             const float* __restrict__ lstep,
                             float* __restrict__ stepv,
                             float* __restrict__ lamv,
                             const float4* __restrict__ Usrc,
                             ushort4* __restrict__ Udst,
                             const float4* __restrict__ Bsrc,
                             ushort4* __restrict__ Bdst,
                             const float4* __restrict__ Csrc,
                             ushort4* __restrict__ Cdst) {
    const int gid = blockIdx.x * 256 + threadIdx.x;
    if (gid < PDIM) {
        stepv[gid] = expf(lstep[gid]);  // STEP_RESCALE = 1.0
        float x = Lraw[gid];
        // jax.nn.softplus(x) = max(x,0) + log1p(exp(-|x|))
        float sp = fmaxf(x, 0.0f) + log1pf(expf(-fabsf(x)));
        lamv[gid] = -(sp + 1e-3f);
    }
    if (gid < NU4) {
        float4 v = Usrc[gid];
        ushort4 o;
        o.x = f2bf(v.x); o.y = f2bf(v.y); o.z = f2bf(v.z); o.w = f2bf(v.w);
        Udst[gid] = o;
    } else {
        const int g2 = gid - NU4;
        if (g2 < NB4) {
            float4 v = Bsrc[g2];
            ushort4 o;
            o.x = f2bf(v.x); o.y = f2bf(v.y); o.z = f2bf(v.z); o.w = f2bf(v.w);
            Bdst[g2] = o;
        } else if (g2 < NB4 + NC4) {
            const int g3 = g2 - NB4;
            float4 v = Csrc[g3];
            ushort4 o;
            o.x = f2bf(v.x); o.y = f2bf(v.y); o.z = f2bf(v.z); o.w = f2bf(v.w);
            Cdst[g3] = o;
        }
    }
}

// ---------------- GEMM1 (8-wave): Bu[m,p] = sum_k u_bf[m,k]*B_bf[p,k], bf16 out.
// SAME 128x128 tile / BK=32 / swizzle / single-barrier dbuf schedule as the
// proven gemm_nt, but split across 8 waves (512 threads): wave tile 64x32,
// 8 MFMA + 2 gl_lds per wave per K-step. Grid 512 = 2 blocks/CU x 8 waves
// -> 16 waves/CU (was 8). GEMM1 is latency-bound (r5: MfmaUtil 9%, HBM 10%);
// doubling resident waves doubles barrier-stall cover WITHOUT changing
// per-block traffic or compute:staging ratio (r3/r6's mistake).
template<int GXL>
__global__ __launch_bounds__(512, 4)
void gemm1_8w(const bf16_t* __restrict__ A, const bf16_t* __restrict__ Bm,
              unsigned short* __restrict__ Cb, int M, int N, int K) {
    __shared__ bf16_t As[2 * 4096];
    __shared__ bf16_t Bs[2 * 4096];

    const int i     = blockIdx.x;
    const int n_blk = (i >> 3) & ((1 << GXL) - 1);
    const int m_blk = ((i >> (3 + GXL)) << 3) | (i & 7);
    const int m0    = m_blk << 7;
    const int n0    = n_blk << 7;

    const int tid  = threadIdx.x;
    const int lane = tid & 63;
    const int w    = tid >> 6;               // 0..7
    const int wm   = (w & 1) << 6;           // 0 / 64
    const int wn   = (w >> 1) << 5;          // 0 / 32 / 64 / 96
    const int r16  = lane & 15;
    const int q    = lane >> 4;
    // conflict-free fragment slot: slot = q ^ g(r16), g(r)=(r+(r>>2))&3  (r7 win)
    const int fsw  = ((q ^ ((r16 + (r16 >> 2)) & 3)) << 3);

    // staging: wave w covers A-rows 16w..16w+15 and B-rows 16w..16w+15
    const int srow = lane >> 2;              // 0..15 within chunk
    const int seg  = (lane & 3) ^ ((srow + (srow >> 2)) & 3);
    const int cw   = w << 4;                 // 16*w

    const bf16_t* gA = A  + (size_t)(m0 + cw + srow) * K + seg * 8;
    const bf16_t* gB = Bm + (size_t)(n0 + cw + srow) * K + seg * 8;
    bf16_t* lA = &As[cw * 32];
    bf16_t* lB = &Bs[cw * 32];

    floatx4 acc[4][2] = {};

    // prologue: stage K-tile 0 into buffer 0
    gl_lds16(gA, lA);
    gl_lds16(gB, lB);
    __syncthreads();

    int cur = 0;
    for (int k0 = 0; k0 < K; k0 += 32) {
        const int nxt = cur ^ 1;
        if (k0 + 32 < K) {
            gl_lds16(gA + k0 + 32, lA + nxt * 4096);
            gl_lds16(gB + k0 + 32, lB + nxt * 4096);
        }

        const bf16_t* rA = As + cur * 4096;
        const bf16_t* rB = Bs + cur * 4096;
        bf16x8 af[4], bfr[2];
#pragma unroll
        for (int ii = 0; ii < 4; ++ii)
            af[ii]  = *(const bf16x8*)&rA[(wm + ii * 16 + r16) * 32 + fsw];
#pragma unroll
        for (int ii = 0; ii < 2; ++ii)
            bfr[ii] = *(const bf16x8*)&rB[(wn + ii * 16 + r16) * 32 + fsw];
#pragma unroll
        for (int mi = 0; mi < 4; ++mi)
#pragma unroll
            for (int ni = 0; ni < 2; ++ni)
                acc[mi][ni] = __builtin_amdgcn_mfma_f32_16x16x32_bf16(
                    af[mi], bfr[ni], acc[mi][ni], 0, 0, 0);

        __syncthreads();
        cur = nxt;
    }

    // epilogue: C/D layout row = q*4 + e, col = r16 (verified); out bf16
#pragma unroll
    for (int mi = 0; mi < 4; ++mi) {
#pragma unroll
        for (int e = 0; e < 4; ++e) {
            const int m = m0 + wm + mi * 16 + q * 4 + e;
#pragma unroll
            for (int ni = 0; ni < 2; ++ni) {
                const int n = n0 + wn + ni * 16 + r16;
                Cb[(size_t)m * N + n] = f2bf(acc[mi][ni][e]);
            }
        }
    }
}

// ---------------- GEMM2 (r11-proven, byte-identical): out = X.C^T + D*u
// 128x128 tile, 4 waves, single-barrier dbuf, conflict-free swizzle,
// D==0 -> exec-mask skips the 32 MB U fetch (correct for any D).
template<int GXL>
__global__ __launch_bounds__(256, 4)
void gemm2_nt(const bf16_t* __restrict__ A, const bf16_t* __restrict__ Bm,
              float* __restrict__ Cf, int M, int N, int K,
              const float* __restrict__ Dv, const float* __restrict__ U32) {
    __shared__ bf16_t As[2 * 4096];
    __shared__ bf16_t Bs[2 * 4096];

    const int i     = blockIdx.x;
    const int n_blk = (i >> 3) & ((1 << GXL) - 1);
    const int m_blk = ((i >> (3 + GXL)) << 3) | (i & 7);
    const int m0    = m_blk << 7;
    const int n0    = n_blk << 7;

    const int tid  = threadIdx.x;
    const int lane = tid & 63;
    const int w    = tid >> 6;
    const int wm   = (w & 1) << 6;
    const int wn   = (w >> 1) << 6;
    const int r16  = lane & 15;
    const int q    = lane >> 4;
    const int fsw  = ((q ^ ((r16 + (r16 >> 2)) & 3)) << 3);

    const int srow = lane >> 2;
    const int seg  = (lane & 3) ^ ((srow + (srow >> 2)) & 3);
    const int c0   = w * 32;
    const int c1   = c0 + 16;

    const bf16_t* gA0 = A  + (size_t)(m0 + c0 + srow) * K + seg * 8;
    const bf16_t* gA1 = A  + (size_t)(m0 + c1 + srow) * K + seg * 8;
    const bf16_t* gB0 = Bm + (size_t)(n0 + c0 + srow) * K + seg * 8;
    const bf16_t* gB1 = Bm + (size_t)(n0 + c1 + srow) * K + seg * 8;
    bf16_t* lA0 = &As[c0 * 32];
    bf16_t* lA1 = &As[c1 * 32];
    bf16_t* lB0 = &Bs[c0 * 32];
    bf16_t* lB1 = &Bs[c1 * 32];

    floatx4 acc[4][4] = {};

    gl_lds16(gA0, lA0);
    gl_lds16(gA1, lA1);
    gl_lds16(gB0, lB0);
    gl_lds16(gB1, lB1);
    __syncthreads();

    int cur = 0;
    for (int k0 = 0; k0 < K; k0 += 32) {
        const int nxt = cur ^ 1;
        if (k0 + 32 < K) {
            gl_lds16(gA0 + k0 + 32, lA0 + nxt * 4096);
            gl_lds16(gA1 + k0 + 32, lA1 + nxt * 4096);
            gl_lds16(gB0 + k0 + 32, lB0 + nxt * 4096);
            gl_lds16(gB1 + k0 + 32, lB1 + nxt * 4096);
        }

        const bf16_t* rA = As + cur * 4096;
        const bf16_t* rB = Bs + cur * 4096;
        bf16x8 af[4], bfr[4];
#pragma unroll
        for (int ii = 0; ii < 4; ++ii) {
            af[ii]  = *(const bf16x8*)&rA[(wm + ii * 16 + r16) * 32 + fsw];
            bfr[ii] = *(const bf16x8*)&rB[(wn + ii * 16 + r16) * 32 + fsw];
        }
#pragma unroll
        for (int mi = 0; mi < 4; ++mi)
#pragma unroll
            for (int ni = 0; ni < 4; ++ni)
                acc[mi][ni] = __builtin_amdgcn_mfma_f32_16x16x32_bf16(
                    af[mi], bfr[ni], acc[mi][ni], 0, 0, 0);

        __syncthreads();
        cur = nxt;
    }

    float dn[4];
#pragma unroll
    for (int ni = 0; ni < 4; ++ni) dn[ni] = Dv[n0 + wn + ni * 16 + r16];
#pragma unroll
    for (int mi = 0; mi < 4; ++mi) {
#pragma unroll
        for (int e = 0; e < 4; ++e) {
            const int m = m0 + wm + mi * 16 + q * 4 + e;
#pragma unroll
            for (int ni = 0; ni < 4; ++ni) {
                const int n = n0 + wn + ni * 16 + r16;
                const size_t idx = (size_t)m * N + n;
                float v = acc[mi][ni][e];
                if (dn[ni] != 0.0f) v += dn[ni] * U32[idx];
                Cf[idx] = v;
            }
        }
    }
}

// ---------------- chunked parallel scan, 2 kernels (r11-proven).
// Recurrence: x_l = abar_l * x_{l-1} + gamma_l * bu_l.
// Phase 1: per (b, chunk, p): P = prod(abar), S = chunk-local x from 0.
__global__ __launch_bounds__(512)
void scan_part1(const unsigned short* __restrict__ Bu, const float* __restrict__ ts,
                const float* __restrict__ stepv, const float* __restrict__ lamv,
                float* __restrict__ Pagg, float* __restrict__ Sagg) {
    const int c = blockIdx.x;
    const int b = blockIdx.y;
    const int p = threadIdx.x;

    const float lam  = lamv[p];
    const float stp  = stepv[p];
    const float rlam = 1.0f / lam;
    const bool  lam_big = fabsf(lam) > 1e-6f;

    const unsigned short* bu = Bu + ((size_t)b * LSEQ + c * CLEN) * PDIM + p;
    const float* tb = ts + b * LSEQ + c * CLEN;

    float P = 1.0f, S = 0.0f;
#pragma unroll 8
    for (int i = 0; i < CLEN; ++i) {
        float t     = tb[i];
        float delta = fmaxf(stp * t, 0.0f);
        float e     = fminf(lam * delta, 20.0f);
        float abar  = __expf(e);
        float gamma = lam_big ? (abar - 1.0f) * rlam : delta;
        S = fmaf(abar, S, gamma * bf2f(bu[(size_t)i * PDIM]));
        P *= abar;
    }
    const size_t o = ((size_t)b * CCH + c) * PDIM + p;
    Pagg[o] = P;
    Sagg[o] = S;
}

// Phase 2+3 fused: replay aggregate scan (entering state), then walk chunk, emit bf16.
__global__ __launch_bounds__(512)
void scan_part23(const unsigned short* __restrict__ Bu, const float* __restrict__ ts,
                 const float* __restrict__ stepv, const float* __restrict__ lamv,
                 const float* __restrict__ Pagg, const float* __restrict__ Sagg,
                 unsigned short* __restrict__ Xbf) {
    const int c = blockIdx.x;
    const int b = blockIdx.y;
    const int p = threadIdx.x;

    const float lam  = lamv[p];
    const float stp  = stepv[p];
    const float rlam = 1.0f / lam;
    const bool  lam_big = fabsf(lam) > 1e-6f;

    const float* Pb = Pagg + (size_t)b * CCH * PDIM + p;
    const float* Sb = Sagg + (size_t)b * CCH * PDIM + p;
    float x = 0.0f;
    int cc = 0;
    for (; cc + 4 <= c; cc += 4) {
        float p0 = Pb[(size_t)(cc + 0) * PDIM], s0 = Sb[(size_t)(cc + 0) * PDIM];
        float p1 = Pb[(size_t)(cc + 1) * PDIM], s1 = Sb[(size_t)(cc + 1) * PDIM];
        float p2 = Pb[(size_t)(cc + 2) * PDIM], s2 = Sb[(size_t)(cc + 2) * PDIM];
        float p3 = Pb[(size_t)(cc + 3) * PDIM], s3 = Sb[(size_t)(cc + 3) * PDIM];
        float p01 = p0 * p1, s01 = fmaf(s0, p1, s1);
        float p23 = p2 * p3, s23 = fmaf(s2, p3, s3);
        float pq  = p01 * p23, sq = fmaf(s01, p23, s23);
        x = fmaf(pq, x, sq);
    }
    for (; cc < c; ++cc) {
        x = fmaf(Pb[(size_t)cc * PDIM], x, Sb[(size_t)cc * PDIM]);
    }

    const unsigned short* bu = Bu + ((size_t)b * LSEQ + c * CLEN) * PDIM + p;
    const float* tb = ts + b * LSEQ + c * CLEN;
    unsigned short* xo = Xbf + ((size_t)b * LSEQ + c * CLEN) * PDIM + p;

#pragma unroll 8
    for (int i = 0; i < CLEN; ++i) {
        float t     = tb[i];
        float delta = fmaxf(stp * t, 0.0f);
        float e     = fminf(lam * delta, 20.0f);
        float abar  = __expf(e);
        float gamma = lam_big ? (abar - 1.0f) * rlam : delta;
        x = fmaf(abar, x, gamma * bf2f(bu[(size_t)i * PDIM]));
        xo[(size_t)i * PDIM] = f2bf(x);
    }
}

extern "C" void kernel_launch(void* const* d_in, const int* in_sizes, int n_in,
                              void* d_out, int out_size, void* d_ws, size_t ws_size,
                              hipStream_t stream) {
    (void)in_sizes; (void)n_in; (void)out_size; (void)ws_size;
    const float* u  = (const float*)d_in[0];
    const float* ts = (const float*)d_in[1];
    const float* Lr = (const float*)d_in[2];
    const float* ls = (const float*)d_in[3];
    const float* Bm = (const float*)d_in[4];
    const float* Cm = (const float*)d_in[5];
    const float* Dv = (const float*)d_in[6];
    float* out = (float*)d_out;

    char* ws = (char*)d_ws;
    bf16_t*         u_bf = (bf16_t*)(ws);                          // 32 MB
    bf16_t*         B_bf = (bf16_t*)(ws + (32u << 20));            // 1 MB
    bf16_t*         C_bf = (bf16_t*)(ws + (33u << 20));            // 1 MB
    unsigned short* Bu   = (unsigned short*)(ws + (34u << 20));    // 16 MB (bf16)
    unsigned short* X_bf = (unsigned short*)(ws + (50u << 20));    // 16 MB
    float*          Pagg = (float*)(ws + (66u << 20));             // 1 MB
    float*          Sagg = (float*)(ws + (67u << 20));             // 1 MB
    float*          stepv= (float*)(ws + (69u << 20));
    float*          lamv = stepv + PDIM;

    // consts + u/B/C casts fused
    setup_kernel<<<(NU4 + NB4 + NC4) / 256, 256, 0, stream>>>(
        Lr, ls, stepv, lamv,
        (const float4*)u,  (ushort4*)u_bf,
        (const float4*)Bm, (ushort4*)B_bf,
        (const float4*)Cm, (ushort4*)C_bf);

    // GEMM1: Bu[16384,512](bf16) = u_bf . B_bf^T   (GXL=2: 4 n-blocks)
    // 512 blocks x 512 threads (8 waves) -> 16 waves/CU
    gemm1_8w<2><<<512, 512, 0, stream>>>(
        u_bf, B_bf, Bu, BLM, PDIM, H_IN);

    // chunked scan -> X (bf16)   (two-kernel version: r12's fused spin-wait
    // variant measured 108 us vs ~23 us -- coherence-fabric thrash; reverted)
    scan_part1<<<dim3(CCH, BSZ), 512, 0, stream>>>(Bu, ts, stepv, lamv, Pagg, Sagg);
    scan_part23<<<dim3(CCH, BSZ), 512, 0, stream>>>(Bu, ts, stepv, lamv,
                                                    Pagg, Sagg, X_bf);

    // GEMM2: out[16384,1024](fp32) = X_bf . C_bf^T + D*u  (GXL=3)
    gemm2_nt<3><<<1024, 256, 0, stream>>>(
        (const bf16_t*)X_bf, C_bf, out, BLM, H_OUTD, PDIM, Dv, u);
}